// Round 14
// baseline (130.146 us; speedup 1.0000x reference)
//
#include <hip/hip_runtime.h>
#include <hip/hip_bf16.h>
#include <math.h>

// Problem constants (fixed by setup_inputs)
#define NX 192
#define NY 192
#define NPIX (NX * NY)     // 36864
#define ETLN 16
#define DATOMS 4000
#define SCH 5              // atom chunks (grid.y)
#define CT 50              // 16-atom tiles per chunk (250/SCH)
#define PXB (NPIX / 128)   // 288 pixel blocks (128 px/block, 32 px/wave)

typedef __attribute__((ext_vector_type(8))) short short8;
typedef __attribute__((ext_vector_type(4))) float f32x4;
typedef unsigned short ushort;
typedef unsigned int uint;
typedef unsigned long long u64;

// ---- ws layout (bytes) ----
// A1  : 4000*64  = 256000    atom rows [Ah(16)|Am(16)] bf16 2-way split
// REC : 4000*64  = 256000    exact f32 atoms (sentinel col = d2)
// TSP : NPIX*64  = 2359296   per-pixel B-frag quads [th0|th1|tm0|tm1]
// TVP : NPIX*64  = 2359296   per-pixel exact tv[16] f32 (sentinel t[z]=1)
// S2P : NPIX*4   = 147456    per-pixel s2
// KEY : NPIX*8   = 294912    u64 argmin keys (monotone-signed bits(f) <<32 | j)
// CNT : PXB*4    = 1152      per-pixel-block completion counters
#define OFF_A1   0
#define OFF_REC  256000
#define OFF_TSP  512000
#define OFF_TVP  2871296
#define OFF_S2P  5230592
#define OFF_KEY  5378048
#define OFF_CNT  5672960
// total 5674112 B

__device__ __forceinline__ int mask_and_z(const float* __restrict__ delta_ms,
                                          float* mask) {
    int z = -1;
#pragma unroll
    for (int e = 0; e < ETLN; ++e) {
        float m = (delta_ms[e] * 1e-3f < 1e-3f) ? 1.0f : 0.0f;
        mask[e] = m;
        if (m == 0.0f && z < 0) z = e;
    }
    return z;
}

// bf16 split: returns bf16 bits of x (RN); *rem = x - float(bf16(x)) (exact)
__device__ __forceinline__ ushort bfsplit(float x, float* rem) {
    __hip_bfloat16 h = __float2bfloat16(x);
    *rem = x - __bfloat162float(h);
    union { __hip_bfloat16 h; ushort u; } cv;
    cv.h = h;
    return cv.u;
}

// Two-stage normalize -> t = -2*s, sentinel t[z]=1 via SELECT (R4 lesson:
// no dynamic-index alloca stores). Reciprocal-mul: 2 divides total.
__device__ __forceinline__ void compute_t(const float* __restrict__ row,
                                          const float* mask, int z,
                                          float* tv, float* s2out) {
    float x[ETLN];
    const float4* r4 = (const float4*)row;
#pragma unroll
    for (int q = 0; q < 4; ++q) {
        float4 a = r4[q];
        x[4 * q + 0] = a.x; x[4 * q + 1] = a.y;
        x[4 * q + 2] = a.z; x[4 * q + 3] = a.w;
    }
    float n1s = 0.f;
#pragma unroll
    for (int e = 0; e < ETLN; ++e) n1s += x[e] * x[e];
    float n1 = sqrtf(n1s);
    float inv1 = (n1 > 0.f) ? (1.0f / n1) : 0.f;
#pragma unroll
    for (int e = 0; e < ETLN; ++e) x[e] = x[e] * inv1 * mask[e];
    float n2s = 0.f;
#pragma unroll
    for (int e = 0; e < ETLN; ++e) n2s += x[e] * x[e];
    float n2 = sqrtf(n2s);
    float inv2 = (n2 > 0.f) ? (1.0f / n2) : 0.f;
    float s2 = 0.f;
#pragma unroll
    for (int e = 0; e < ETLN; ++e) {
        float y = x[e] * inv2;
        s2 += y * y;
        float t = -2.0f * y;
        tv[e] = (e == z) ? 1.0f : t;
    }
    *s2out = s2;
}

// prep: pixels -> tsp (bf16 frag quads) + tvp/s2p (exact) + key init;
//       atoms -> A1 (2-way split rows) + recf (exact, sentinel col = d2);
//       counters -> 0
__global__ __launch_bounds__(256) void prep(
        const float* __restrict__ sig, const float* __restrict__ db_mag,
        const float* __restrict__ delta_ms,
        ushort* __restrict__ A1, float* __restrict__ recf,
        ushort* __restrict__ tsp, float* __restrict__ tvp,
        float* __restrict__ s2p, u64* __restrict__ keys,
        uint* __restrict__ cnt) {
    int t = blockIdx.x * 256 + threadIdx.x;
    float mask[ETLN];
    int z = mask_and_z(delta_ms, mask);

    if (t < PXB) cnt[t] = 0u;   // completion counters (ws is 0xAA-poisoned)

    if (t < NPIX) {
        keys[t] = 0xFFFFFFFFFFFFFFFFull;
        float tv[ETLN], s2;
        compute_t(sig + (size_t)t * ETLN, mask, z, tv, &s2);
        s2p[t] = s2;
#pragma unroll
        for (int e = 0; e < ETLN; ++e) tvp[(size_t)t * ETLN + e] = tv[e];
        // frag quads: [th0(8) | th1(8) | tm0(8) | tm1(8)] bf16
#pragma unroll
        for (int e = 0; e < ETLN; ++e) {
            float r1, dmy;
            ushort hb = bfsplit(tv[e], &r1);
            ushort mb = bfsplit(r1, &dmy);
            tsp[(size_t)t * 32 + e]      = hb;   // th0|th1
            tsp[(size_t)t * 32 + 16 + e] = mb;   // tm0|tm1
        }
    }

    if (t < DATOMS) {
        float v[ETLN];
        float ss = 0.f;
#pragma unroll
        for (int e = 0; e < ETLN; ++e) {
            float x = db_mag[t * ETLN + e] * mask[e];
            v[e] = x;
            ss += x * x;
        }
        float n = sqrtf(ss);
        float inv = (n > 0.f) ? (1.0f / n) : 0.f;
        float d2 = 0.f;
#pragma unroll
        for (int e = 0; e < ETLN; ++e) {
            float y = v[e] * inv;
            v[e] = y;
            d2 += y * y;
        }
#pragma unroll
        for (int e = 0; e < ETLN; ++e) {
            float w = (e == z) ? d2 : v[e];   // sentinel col carries d2
            recf[t * ETLN + e] = w;
            float r1, dmy;
            ushort hb = bfsplit(w, &r1);
            ushort mb = bfsplit(r1, &dmy);
            A1[t * 32 + e]      = hb;   // Ah
            A1[t * 32 + 16 + e] = mb;   // Am
        }
    }
}

// Approx filter key. cinit = 1.0 -> MFMA emits f' = 1 + d2 - 2*dot = dist^2
// > 0 (s2 = 1): positive f32 -> raw bits u32-monotone. <<1 drops the
// constant-0 sign bit; low 12 bits replaced by atom index. Quantum ~7.6e-6
// at the minima -- below the ~2e-5 split noise the exact-rescore rescue
// absorbs.
__device__ __forceinline__ void top2_update(f32x4 acc, uint i0, uint i1,
                                            uint i2, uint i3,
                                            uint* k1, uint* k2) {
    uint kk0 = ((__float_as_uint(acc[0]) << 1) & 0xFFFFF000u) | i0;
    uint kk1 = ((__float_as_uint(acc[1]) << 1) & 0xFFFFF000u) | i1;
    uint kk2 = ((__float_as_uint(acc[2]) << 1) & 0xFFFFF000u) | i2;
    uint kk3 = ((__float_as_uint(acc[3]) << 1) & 0xFFFFF000u) | i3;
    uint t3 = min(min(kk0, kk1), min(kk2, kk3));
    bool lt = t3 < *k1;
    uint mn2 = min(*k2, t3);
    *k2 = lt ? *k1 : mn2;
    *k1 = min(*k1, t3);
}

// Score one 2-tile pair (32 atoms x 32 pixels): 8 MFMA + 4 top2_update.
__device__ __forceinline__ void proc_pair(
        short8 t0, short8 t1, short8 V1A, short8 V2A, short8 V1B, short8 V2B,
        f32x4 cinit, uint i0, uint i1, uint i2, uint i3,
        uint* k1A, uint* k2A, uint* k1B, uint* k2B) {
    f32x4 a00 = __builtin_amdgcn_mfma_f32_16x16x32_bf16(t0, V1A, cinit, 0, 0, 0);
    f32x4 a01 = __builtin_amdgcn_mfma_f32_16x16x32_bf16(t0, V1B, cinit, 0, 0, 0);
    f32x4 a10 = __builtin_amdgcn_mfma_f32_16x16x32_bf16(t1, V1A, cinit, 0, 0, 0);
    f32x4 a11 = __builtin_amdgcn_mfma_f32_16x16x32_bf16(t1, V1B, cinit, 0, 0, 0);
    a00 = __builtin_amdgcn_mfma_f32_16x16x32_bf16(t0, V2A, a00, 0, 0, 0);
    a01 = __builtin_amdgcn_mfma_f32_16x16x32_bf16(t0, V2B, a01, 0, 0, 0);
    a10 = __builtin_amdgcn_mfma_f32_16x16x32_bf16(t1, V2A, a10, 0, 0, 0);
    a11 = __builtin_amdgcn_mfma_f32_16x16x32_bf16(t1, V2B, a11, 0, 0, 0);
    asm("" : "+v"(a00), "+v"(a01), "+v"(a10), "+v"(a11));
    top2_update(a00, i0,       i1,       i2,       i3,       k1A, k2A);
    top2_update(a01, i0,       i1,       i2,       i3,       k1B, k2B);
    top2_update(a10, i0 + 16u, i1 + 16u, i2 + 16u, i3 + 16u, k1A, k2A);
    top2_update(a11, i0 + 16u, i1 + 16u, i2 + 16u, i3 + 16u, k1B, k2B);
}

__device__ __forceinline__ float dot16(const float* __restrict__ rr,
                                       float4 t0, float4 t1, float4 t2, float4 t3) {
    const float4* r4 = (const float4*)rr;
    float4 a0 = r4[0], a1 = r4[1], a2 = r4[2], a3 = r4[3];
    float f = 0.f;
    f = fmaf(a0.x, t0.x, f); f = fmaf(a0.y, t0.y, f);
    f = fmaf(a0.z, t0.z, f); f = fmaf(a0.w, t0.w, f);
    f = fmaf(a1.x, t1.x, f); f = fmaf(a1.y, t1.y, f);
    f = fmaf(a1.z, t1.z, f); f = fmaf(a1.w, t1.w, f);
    f = fmaf(a2.x, t2.x, f); f = fmaf(a2.y, t2.y, f);
    f = fmaf(a2.z, t2.z, f); f = fmaf(a2.w, t2.w, f);
    f = fmaf(a3.x, t3.x, f); f = fmaf(a3.y, t3.y, f);
    f = fmaf(a3.z, t3.z, f); f = fmaf(a3.w, t3.w, f);
    return f;   // = d2 - 2*dot (sentinel col in rr, tv[z]=1)
}

// Monotone total-order map for signed f32 (R9-verified selection semantics).
__device__ __forceinline__ uint fmono(float f) {
    uint b = __float_as_uint(f);
    return b ^ (uint)(((int)b >> 31) | 0x80000000);
}

// match: 32 px/wave x one 800-atom chunk. Ping-pong 4-tile pipeline (R13).
// NEW: fused finalize -- per-pixel-block completion counter; the last of the
// SCH blocks (release fence -> atomicAdd -> acquire fence) decodes the keys
// for its 128 pixels and writes the outputs. Kills the finalize dispatch.
__global__ __launch_bounds__(256, 4) void match(
        const ushort* __restrict__ A1, const ushort* __restrict__ tsp,
        const float* __restrict__ recf, const float* __restrict__ tvp,
        const float* __restrict__ s2p, u64* __restrict__ keys,
        uint* __restrict__ cnt, const float* __restrict__ t2s,
        const float* __restrict__ b1s, float* __restrict__ out) {
    const int lane = threadIdx.x & 63;
    const int wv   = threadIdx.x >> 6;
    const int quad = lane >> 4;
    const int l15  = lane & 15;

    const int pA = blockIdx.x * 128 + wv * 32 + l15;
    const int pB = pA + 16;
    // V1 = [th|tm] variant table[quad] at quad*16B; V2 = table[quad^2]
    const char* tp = (const char*)tsp;
    short8 V1A = *(const short8*)(tp + (size_t)pA * 64 + quad * 16);
    short8 V2A = *(const short8*)(tp + (size_t)pA * 64 + (quad ^ 2) * 16);
    short8 V1B = *(const short8*)(tp + (size_t)pB * 64 + quad * 16);
    short8 V2B = *(const short8*)(tp + (size_t)pB * 64 + (quad ^ 2) * 16);
    asm("" : "+v"(V1A), "+v"(V2A), "+v"(V1B), "+v"(V2B));

    uint k1A = 0xFFFFFFFFu, k2A = 0xFFFFFFFFu;
    uint k1B = 0xFFFFFFFFu, k2B = 0xFFFFFFFFu;

    const int jbase = blockIdx.y * (CT * 16);
    const char* abase = (const char*)A1 + (size_t)jbase * 64 + l15 * 64 + quad * 16;
    const f32x4 cinit = (f32x4){1.0f, 1.0f, 1.0f, 1.0f};   // f' = dist^2

    // per-row atom indices for this lane's C rows, advanced +32 per pair
    uint i0 = (uint)(jbase + quad * 4);
    uint i1 = i0 + 1u, i2 = i0 + 2u, i3 = i0 + 3u;

    // prime: x = tiles 0,1; y = tiles 2,3; W walks, pointing at next x-tile
    short8 x0 = *(const short8*)(abase);
    short8 x1 = *(const short8*)(abase + 1024);
    short8 y0 = *(const short8*)(abase + 2048);
    short8 y1 = *(const short8*)(abase + 3072);
    const char* W = abase + 4096;

#pragma unroll 1
    for (int it = 0; it < 11; ++it) {
        asm("" : "+v"(x0), "+v"(x1));
        proc_pair(x0, x1, V1A, V2A, V1B, V2B, cinit, i0, i1, i2, i3,
                  &k1A, &k2A, &k1B, &k2B);
        i0 += 32u; i1 += 32u; i2 += 32u; i3 += 32u;
        x0 = *(const short8*)(W);            // tiles 4it+4, 4it+5
        x1 = *(const short8*)(W + 1024);
        asm("" : "+v"(y0), "+v"(y1));
        proc_pair(y0, y1, V1A, V2A, V1B, V2B, cinit, i0, i1, i2, i3,
                  &k1A, &k2A, &k1B, &k2B);
        i0 += 32u; i1 += 32u; i2 += 32u; i3 += 32u;
        y0 = *(const short8*)(W + 2048);     // tiles 4it+6, 4it+7
        y1 = *(const short8*)(W + 3072);
        W += 4096;
    }
    // tail: x = tiles 44,45; y = 46,47; W -> tile 48
    proc_pair(x0, x1, V1A, V2A, V1B, V2B, cinit, i0, i1, i2, i3,
              &k1A, &k2A, &k1B, &k2B);
    i0 += 32u; i1 += 32u; i2 += 32u; i3 += 32u;
    proc_pair(y0, y1, V1A, V2A, V1B, V2B, cinit, i0, i1, i2, i3,
              &k1A, &k2A, &k1B, &k2B);
    i0 += 32u; i1 += 32u; i2 += 32u; i3 += 32u;
    short8 z0 = *(const short8*)(W);
    short8 z1 = *(const short8*)(W + 1024);
    proc_pair(z0, z1, V1A, V2A, V1B, V2B, cinit, i0, i1, i2, i3,
              &k1A, &k2A, &k1B, &k2B);

    // Cross-quad top-2 merge (disjoint atom sets per quad), then exact rescore.
#pragma unroll
    for (int g = 0; g < 2; ++g) {
        uint p1 = g ? k1B : k1A;
        uint p2 = g ? k2B : k2A;
#pragma unroll
        for (int off = 16; off <= 32; off <<= 1) {
            uint o1 = (uint)__shfl_xor((int)p1, off);
            uint o2 = (uint)__shfl_xor((int)p2, off);
            uint n1 = p1 < o1 ? p1 : o1;
            uint mx = p1 < o1 ? o1 : p1;
            uint mn = p2 < o2 ? p2 : o2;
            p2 = mx < mn ? mx : mn;
            p1 = n1;
        }
        if (lane < 16) {
            int px = blockIdx.x * 128 + wv * 32 + lane + (g ? 16 : 0);
            int j1 = (int)(p1 & 0xFFFu);
            int j2 = (int)(p2 & 0xFFFu);
            const float4* tq = (const float4*)(tvp + (size_t)px * ETLN);
            float4 t0 = tq[0], t1 = tq[1], t2 = tq[2], t3 = tq[3];
            float f1 = dot16(recf + (size_t)j1 * ETLN, t0, t1, t2, t3);
            float f2 = dot16(recf + (size_t)j2 * ETLN, t0, t1, t2, t3);
            u64 key1 = (((u64)fmono(f1)) << 32) | (uint)j1;
            u64 key2 = (((u64)fmono(f2)) << 32) | (uint)j2;
            atomicMin(&keys[px], key1 < key2 ? key1 : key2);
        }
    }

    // Fused finalize: last of the SCH blocks for this pixel-block writes out.
    __shared__ int lastflag;
    __syncthreads();                 // all waves' atomicMins issued
    if (threadIdx.x == 0) {
        __threadfence();             // release: our atomics visible device-wide
        uint old = atomicAdd(&cnt[blockIdx.x], 1u);
        lastflag = (old == SCH - 1u);
    }
    __syncthreads();
    if (lastflag) {
        __threadfence();             // acquire: other blocks' atomics visible
        int i = threadIdx.x;
        if (i < 128) {
            int p = blockIdx.x * 128 + i;
            u64 k = keys[p];
            int j = (int)(k & 0xFFFu);
            uint mb = (uint)(k >> 32);
            uint b = (mb & 0x80000000u) ? (mb ^ 0x80000000u) : ~mb; // un-fmono
            float f = __uint_as_float(b);
            out[p] = t2s[j];
            out[NPIX + p] = b1s[j];
            out[2 * NPIX + p] = sqrtf(fmaxf(f + s2p[p], 0.0f));
        }
    }
}

extern "C" void kernel_launch(void* const* d_in, const int* in_sizes, int n_in,
                              void* d_out, int out_size, void* d_ws, size_t ws_size,
                              hipStream_t stream) {
    const float* sig    = (const float*)d_in[0];  // [192,192,16]
    const float* db_mag = (const float*)d_in[1];  // [4000,16]
    const float* t2s    = (const float*)d_in[2];  // [4000]
    const float* b1s    = (const float*)d_in[3];  // [4000]
    const float* delta  = (const float*)d_in[4];  // [16]

    char* ws = (char*)d_ws;
    ushort* A1   = (ushort*)(ws + OFF_A1);
    float*  recf = (float*)(ws + OFF_REC);
    ushort* tsp  = (ushort*)(ws + OFF_TSP);
    float*  tvp  = (float*)(ws + OFF_TVP);
    float*  s2p  = (float*)(ws + OFF_S2P);
    u64*    keys = (u64*)(ws + OFF_KEY);
    uint*   cnt  = (uint*)(ws + OFF_CNT);

    prep<<<PXB / 2, 256, 0, stream>>>(sig, db_mag, delta, A1, recf, tsp, tvp,
                                      s2p, keys, cnt);
    dim3 grid(PXB, SCH);
    match<<<grid, 256, 0, stream>>>(A1, tsp, recf, tvp, s2p, keys, cnt,
                                    t2s, b1s, (float*)d_out);
}

// Round 15
// 97.143 us; speedup vs baseline: 1.3397x; 1.3397x over previous
//
#include <hip/hip_runtime.h>
#include <hip/hip_bf16.h>
#include <math.h>

// Problem constants (fixed by setup_inputs)
#define NX 192
#define NY 192
#define NPIX (NX * NY)     // 36864
#define ETLN 16
#define DATOMS 4000
#define SCH 5              // atom chunks (grid.y)
#define CT 50              // 16-atom tiles per chunk (250/SCH)
#define PXB (NPIX / 128)   // 288 pixel blocks (128 px/block, 32 px/wave)

typedef __attribute__((ext_vector_type(8))) short short8;
typedef __attribute__((ext_vector_type(4))) float f32x4;
typedef unsigned short ushort;
typedef unsigned int uint;
typedef unsigned long long u64;

// ---- ws layout (bytes) ----
// A1  : 4000*64  = 256000    atom rows [Ah(16)|Am(16)] bf16 2-way split
// REC : 4000*64  = 256000    exact f32 atoms (sentinel col = d2)
// TSP : NPIX*64  = 2359296   per-pixel B-frag quads [th0|th1|tm0|tm1]
// TVP : NPIX*64  = 2359296   per-pixel exact tv[16] f32 (sentinel t[z]=1)
// S2P : NPIX*4   = 147456    per-pixel s2
// KEY : NPIX*8   = 294912    u64 argmin keys (monotone-signed bits(f) <<32 | j)
#define OFF_A1   0
#define OFF_REC  256000
#define OFF_TSP  512000
#define OFF_TVP  2871296
#define OFF_S2P  5230592
#define OFF_KEY  5378048
// total 5672960 B

// R14 LESSON: fusing finalize into match via a last-block-done protocol
// (counter + threadfence) regressed 97.7 -> 130 us: the 288 "last" blocks
// stack epilogue + fence + scattered gathers serially onto the final
// scheduling round. Keep finalize as its own dispatch.

__device__ __forceinline__ int mask_and_z(const float* __restrict__ delta_ms,
                                          float* mask) {
    int z = -1;
#pragma unroll
    for (int e = 0; e < ETLN; ++e) {
        float m = (delta_ms[e] * 1e-3f < 1e-3f) ? 1.0f : 0.0f;
        mask[e] = m;
        if (m == 0.0f && z < 0) z = e;
    }
    return z;
}

// bf16 split: returns bf16 bits of x (RN); *rem = x - float(bf16(x)) (exact)
__device__ __forceinline__ ushort bfsplit(float x, float* rem) {
    __hip_bfloat16 h = __float2bfloat16(x);
    *rem = x - __bfloat162float(h);
    union { __hip_bfloat16 h; ushort u; } cv;
    cv.h = h;
    return cv.u;
}

// Two-stage normalize -> t = -2*s, sentinel t[z]=1 via SELECT (R4 lesson:
// no dynamic-index alloca stores). Reciprocal-mul: 2 divides total.
__device__ __forceinline__ void compute_t(const float* __restrict__ row,
                                          const float* mask, int z,
                                          float* tv, float* s2out) {
    float x[ETLN];
    const float4* r4 = (const float4*)row;
#pragma unroll
    for (int q = 0; q < 4; ++q) {
        float4 a = r4[q];
        x[4 * q + 0] = a.x; x[4 * q + 1] = a.y;
        x[4 * q + 2] = a.z; x[4 * q + 3] = a.w;
    }
    float n1s = 0.f;
#pragma unroll
    for (int e = 0; e < ETLN; ++e) n1s += x[e] * x[e];
    float n1 = sqrtf(n1s);
    float inv1 = (n1 > 0.f) ? (1.0f / n1) : 0.f;
#pragma unroll
    for (int e = 0; e < ETLN; ++e) x[e] = x[e] * inv1 * mask[e];
    float n2s = 0.f;
#pragma unroll
    for (int e = 0; e < ETLN; ++e) n2s += x[e] * x[e];
    float n2 = sqrtf(n2s);
    float inv2 = (n2 > 0.f) ? (1.0f / n2) : 0.f;
    float s2 = 0.f;
#pragma unroll
    for (int e = 0; e < ETLN; ++e) {
        float y = x[e] * inv2;
        s2 += y * y;
        float t = -2.0f * y;
        tv[e] = (e == z) ? 1.0f : t;
    }
    *s2out = s2;
}

// prep: pixels -> tsp (bf16 frag quads) + tvp/s2p (exact) + key init;
//       atoms -> A1 (2-way split rows) + recf (exact, sentinel col = d2)
__global__ __launch_bounds__(256) void prep(
        const float* __restrict__ sig, const float* __restrict__ db_mag,
        const float* __restrict__ delta_ms,
        ushort* __restrict__ A1, float* __restrict__ recf,
        ushort* __restrict__ tsp, float* __restrict__ tvp,
        float* __restrict__ s2p, u64* __restrict__ keys) {
    int t = blockIdx.x * 256 + threadIdx.x;
    float mask[ETLN];
    int z = mask_and_z(delta_ms, mask);

    if (t < NPIX) {
        keys[t] = 0xFFFFFFFFFFFFFFFFull;
        float tv[ETLN], s2;
        compute_t(sig + (size_t)t * ETLN, mask, z, tv, &s2);
        s2p[t] = s2;
#pragma unroll
        for (int e = 0; e < ETLN; ++e) tvp[(size_t)t * ETLN + e] = tv[e];
        // frag quads: [th0(8) | th1(8) | tm0(8) | tm1(8)] bf16
#pragma unroll
        for (int e = 0; e < ETLN; ++e) {
            float r1, dmy;
            ushort hb = bfsplit(tv[e], &r1);
            ushort mb = bfsplit(r1, &dmy);
            tsp[(size_t)t * 32 + e]      = hb;   // th0|th1
            tsp[(size_t)t * 32 + 16 + e] = mb;   // tm0|tm1
        }
    }

    if (t < DATOMS) {
        float v[ETLN];
        float ss = 0.f;
#pragma unroll
        for (int e = 0; e < ETLN; ++e) {
            float x = db_mag[t * ETLN + e] * mask[e];
            v[e] = x;
            ss += x * x;
        }
        float n = sqrtf(ss);
        float inv = (n > 0.f) ? (1.0f / n) : 0.f;
        float d2 = 0.f;
#pragma unroll
        for (int e = 0; e < ETLN; ++e) {
            float y = v[e] * inv;
            v[e] = y;
            d2 += y * y;
        }
#pragma unroll
        for (int e = 0; e < ETLN; ++e) {
            float w = (e == z) ? d2 : v[e];   // sentinel col carries d2
            recf[t * ETLN + e] = w;
            float r1, dmy;
            ushort hb = bfsplit(w, &r1);
            ushort mb = bfsplit(r1, &dmy);
            A1[t * 32 + e]      = hb;   // Ah
            A1[t * 32 + 16 + e] = mb;   // Am
        }
    }
}

// Approx filter key. cinit = 1.0 -> MFMA emits f' = 1 + d2 - 2*dot = dist^2
// > 0 (s2 = 1): positive f32 -> raw bits u32-monotone. <<1 drops the
// constant-0 sign bit; low 12 bits replaced by atom index. Quantum ~7.6e-6
// at the minima -- below the ~2e-5 split noise the exact-rescore rescue
// absorbs. min-tree form lets the compiler emit v_min3_u32.
__device__ __forceinline__ void top2_update(f32x4 acc, uint i0, uint i1,
                                            uint i2, uint i3,
                                            uint* k1, uint* k2) {
    uint kk0 = ((__float_as_uint(acc[0]) << 1) & 0xFFFFF000u) | i0;
    uint kk1 = ((__float_as_uint(acc[1]) << 1) & 0xFFFFF000u) | i1;
    uint kk2 = ((__float_as_uint(acc[2]) << 1) & 0xFFFFF000u) | i2;
    uint kk3 = ((__float_as_uint(acc[3]) << 1) & 0xFFFFF000u) | i3;
    uint t3 = min(min(kk0, kk1), min(kk2, kk3));
    bool lt = t3 < *k1;
    uint mn2 = min(*k2, t3);
    *k2 = lt ? *k1 : mn2;
    *k1 = min(*k1, t3);
}

// Score one 2-tile pair (32 atoms x 32 pixels): 8 MFMA + 4 top2_update.
__device__ __forceinline__ void proc_pair(
        short8 t0, short8 t1, short8 V1A, short8 V2A, short8 V1B, short8 V2B,
        f32x4 cinit, uint i0, uint i1, uint i2, uint i3,
        uint* k1A, uint* k2A, uint* k1B, uint* k2B) {
    f32x4 a00 = __builtin_amdgcn_mfma_f32_16x16x32_bf16(t0, V1A, cinit, 0, 0, 0);
    f32x4 a01 = __builtin_amdgcn_mfma_f32_16x16x32_bf16(t0, V1B, cinit, 0, 0, 0);
    f32x4 a10 = __builtin_amdgcn_mfma_f32_16x16x32_bf16(t1, V1A, cinit, 0, 0, 0);
    f32x4 a11 = __builtin_amdgcn_mfma_f32_16x16x32_bf16(t1, V1B, cinit, 0, 0, 0);
    a00 = __builtin_amdgcn_mfma_f32_16x16x32_bf16(t0, V2A, a00, 0, 0, 0);
    a01 = __builtin_amdgcn_mfma_f32_16x16x32_bf16(t0, V2B, a01, 0, 0, 0);
    a10 = __builtin_amdgcn_mfma_f32_16x16x32_bf16(t1, V2A, a10, 0, 0, 0);
    a11 = __builtin_amdgcn_mfma_f32_16x16x32_bf16(t1, V2B, a11, 0, 0, 0);
    asm("" : "+v"(a00), "+v"(a01), "+v"(a10), "+v"(a11));
    top2_update(a00, i0,       i1,       i2,       i3,       k1A, k2A);
    top2_update(a01, i0,       i1,       i2,       i3,       k1B, k2B);
    top2_update(a10, i0 + 16u, i1 + 16u, i2 + 16u, i3 + 16u, k1A, k2A);
    top2_update(a11, i0 + 16u, i1 + 16u, i2 + 16u, i3 + 16u, k1B, k2B);
}

__device__ __forceinline__ float dot16(const float* __restrict__ rr,
                                       float4 t0, float4 t1, float4 t2, float4 t3) {
    const float4* r4 = (const float4*)rr;
    float4 a0 = r4[0], a1 = r4[1], a2 = r4[2], a3 = r4[3];
    float f = 0.f;
    f = fmaf(a0.x, t0.x, f); f = fmaf(a0.y, t0.y, f);
    f = fmaf(a0.z, t0.z, f); f = fmaf(a0.w, t0.w, f);
    f = fmaf(a1.x, t1.x, f); f = fmaf(a1.y, t1.y, f);
    f = fmaf(a1.z, t1.z, f); f = fmaf(a1.w, t1.w, f);
    f = fmaf(a2.x, t2.x, f); f = fmaf(a2.y, t2.y, f);
    f = fmaf(a2.z, t2.z, f); f = fmaf(a2.w, t2.w, f);
    f = fmaf(a3.x, t3.x, f); f = fmaf(a3.y, t3.y, f);
    f = fmaf(a3.z, t3.z, f); f = fmaf(a3.w, t3.w, f);
    return f;   // = d2 - 2*dot (sentinel col in rr, tv[z]=1)
}

// Monotone total-order map for signed f32 (R9-verified selection semantics).
__device__ __forceinline__ uint fmono(float f) {
    uint b = __float_as_uint(f);
    return b ^ (uint)(((int)b >> 31) | 0x80000000);
}

// match: 32 px/wave x one 800-atom chunk. Ping-pong 4-tile pipeline (R13):
// two named buffer pairs -- loads land in their consumption registers, zero
// rotate movs; one walking pointer + immediate offsets. 11 iters + 6-tile
// tail = CT 50. Exact-rescore tail + u64 atomicMin (R9 fmono semantics).
__global__ __launch_bounds__(256, 4) void match(
        const ushort* __restrict__ A1, const ushort* __restrict__ tsp,
        const float* __restrict__ recf, const float* __restrict__ tvp,
        u64* __restrict__ keys) {
    const int lane = threadIdx.x & 63;
    const int wv   = threadIdx.x >> 6;
    const int quad = lane >> 4;
    const int l15  = lane & 15;

    const int pA = blockIdx.x * 128 + wv * 32 + l15;
    const int pB = pA + 16;
    // V1 = [th|tm] variant table[quad] at quad*16B; V2 = table[quad^2]
    const char* tp = (const char*)tsp;
    short8 V1A = *(const short8*)(tp + (size_t)pA * 64 + quad * 16);
    short8 V2A = *(const short8*)(tp + (size_t)pA * 64 + (quad ^ 2) * 16);
    short8 V1B = *(const short8*)(tp + (size_t)pB * 64 + quad * 16);
    short8 V2B = *(const short8*)(tp + (size_t)pB * 64 + (quad ^ 2) * 16);
    asm("" : "+v"(V1A), "+v"(V2A), "+v"(V1B), "+v"(V2B));

    uint k1A = 0xFFFFFFFFu, k2A = 0xFFFFFFFFu;
    uint k1B = 0xFFFFFFFFu, k2B = 0xFFFFFFFFu;

    const int jbase = blockIdx.y * (CT * 16);
    const char* abase = (const char*)A1 + (size_t)jbase * 64 + l15 * 64 + quad * 16;
    const f32x4 cinit = (f32x4){1.0f, 1.0f, 1.0f, 1.0f};   // f' = dist^2

    // per-row atom indices for this lane's C rows, advanced +32 per pair
    uint i0 = (uint)(jbase + quad * 4);
    uint i1 = i0 + 1u, i2 = i0 + 2u, i3 = i0 + 3u;

    // prime: x = tiles 0,1; y = tiles 2,3; W walks, pointing at next x-tile
    short8 x0 = *(const short8*)(abase);
    short8 x1 = *(const short8*)(abase + 1024);
    short8 y0 = *(const short8*)(abase + 2048);
    short8 y1 = *(const short8*)(abase + 3072);
    const char* W = abase + 4096;

#pragma unroll 1
    for (int it = 0; it < 11; ++it) {
        asm("" : "+v"(x0), "+v"(x1));
        proc_pair(x0, x1, V1A, V2A, V1B, V2B, cinit, i0, i1, i2, i3,
                  &k1A, &k2A, &k1B, &k2B);
        i0 += 32u; i1 += 32u; i2 += 32u; i3 += 32u;
        x0 = *(const short8*)(W);            // tiles 4it+4, 4it+5
        x1 = *(const short8*)(W + 1024);
        asm("" : "+v"(y0), "+v"(y1));
        proc_pair(y0, y1, V1A, V2A, V1B, V2B, cinit, i0, i1, i2, i3,
                  &k1A, &k2A, &k1B, &k2B);
        i0 += 32u; i1 += 32u; i2 += 32u; i3 += 32u;
        y0 = *(const short8*)(W + 2048);     // tiles 4it+6, 4it+7
        y1 = *(const short8*)(W + 3072);
        W += 4096;
    }
    // tail: x = tiles 44,45; y = 46,47; W -> tile 48
    proc_pair(x0, x1, V1A, V2A, V1B, V2B, cinit, i0, i1, i2, i3,
              &k1A, &k2A, &k1B, &k2B);
    i0 += 32u; i1 += 32u; i2 += 32u; i3 += 32u;
    proc_pair(y0, y1, V1A, V2A, V1B, V2B, cinit, i0, i1, i2, i3,
              &k1A, &k2A, &k1B, &k2B);
    i0 += 32u; i1 += 32u; i2 += 32u; i3 += 32u;
    short8 z0 = *(const short8*)(W);
    short8 z1 = *(const short8*)(W + 1024);
    proc_pair(z0, z1, V1A, V2A, V1B, V2B, cinit, i0, i1, i2, i3,
              &k1A, &k2A, &k1B, &k2B);

    // Cross-quad top-2 merge (disjoint atom sets per quad), then exact rescore.
#pragma unroll
    for (int g = 0; g < 2; ++g) {
        uint p1 = g ? k1B : k1A;
        uint p2 = g ? k2B : k2A;
#pragma unroll
        for (int off = 16; off <= 32; off <<= 1) {
            uint o1 = (uint)__shfl_xor((int)p1, off);
            uint o2 = (uint)__shfl_xor((int)p2, off);
            uint n1 = p1 < o1 ? p1 : o1;
            uint mx = p1 < o1 ? o1 : p1;
            uint mn = p2 < o2 ? p2 : o2;
            p2 = mx < mn ? mx : mn;
            p1 = n1;
        }
        if (lane < 16) {
            int px = blockIdx.x * 128 + wv * 32 + lane + (g ? 16 : 0);
            int j1 = (int)(p1 & 0xFFFu);
            int j2 = (int)(p2 & 0xFFFu);
            const float4* tq = (const float4*)(tvp + (size_t)px * ETLN);
            float4 t0 = tq[0], t1 = tq[1], t2 = tq[2], t3 = tq[3];
            float f1 = dot16(recf + (size_t)j1 * ETLN, t0, t1, t2, t3);
            float f2 = dot16(recf + (size_t)j2 * ETLN, t0, t1, t2, t3);
            u64 key1 = (((u64)fmono(f1)) << 32) | (uint)j1;
            u64 key2 = (((u64)fmono(f2)) << 32) | (uint)j2;
            atomicMin(&keys[px], key1 < key2 ? key1 : key2);
        }
    }
}

// finalize: decode winner key (monotone f bits, j) -> outputs
__global__ __launch_bounds__(256) void finalize(
        const u64* __restrict__ keys, const float* __restrict__ s2p,
        const float* __restrict__ t2s, const float* __restrict__ b1s,
        float* __restrict__ out) {
    int p = blockIdx.x * 256 + threadIdx.x;
    if (p >= NPIX) return;
    u64 k = keys[p];
    int j = (int)(k & 0xFFFu);
    uint mb = (uint)(k >> 32);
    uint b = (mb & 0x80000000u) ? (mb ^ 0x80000000u) : ~mb;  // inverse of fmono
    float f = __uint_as_float(b);
    out[p] = t2s[j];
    out[NPIX + p] = b1s[j];
    out[2 * NPIX + p] = sqrtf(fmaxf(f + s2p[p], 0.0f));
}

extern "C" void kernel_launch(void* const* d_in, const int* in_sizes, int n_in,
                              void* d_out, int out_size, void* d_ws, size_t ws_size,
                              hipStream_t stream) {
    const float* sig    = (const float*)d_in[0];  // [192,192,16]
    const float* db_mag = (const float*)d_in[1];  // [4000,16]
    const float* t2s    = (const float*)d_in[2];  // [4000]
    const float* b1s    = (const float*)d_in[3];  // [4000]
    const float* delta  = (const float*)d_in[4];  // [16]

    char* ws = (char*)d_ws;
    ushort* A1   = (ushort*)(ws + OFF_A1);
    float*  recf = (float*)(ws + OFF_REC);
    ushort* tsp  = (ushort*)(ws + OFF_TSP);
    float*  tvp  = (float*)(ws + OFF_TVP);
    float*  s2p  = (float*)(ws + OFF_S2P);
    u64*    keys = (u64*)(ws + OFF_KEY);

    prep<<<PXB / 2, 256, 0, stream>>>(sig, db_mag, delta, A1, recf, tsp, tvp,
                                      s2p, keys);
    dim3 grid(PXB, SCH);
    match<<<grid, 256, 0, stream>>>(A1, tsp, recf, tvp, keys);
    finalize<<<PXB / 2, 256, 0, stream>>>(keys, s2p, t2s, b1s, (float*)d_out);
}